// Round 2
// baseline (351.519 us; speedup 1.0000x reference)
//
#include <hip/hip_runtime.h>
#include <math.h>

// (P, C, NX, NY, NT) = (2, 1, 128, 128, 8), T = 128
// Layout: idx = pp<<17 | X<<10 | Y<<3 | T
// R1 rewrite: T-column-per-thread. Each thread owns all 8 T of one (x,y)
// column: T-neighbors (xbtp/xbtm/q2tm/lamt) are in-register rotations (no
// shfl), LDS staging is b128-vectorized (float4 xb + ulonglong2 qq planes).
// Tile: own 8x16, halo 4, staged 16x24 = 384 threads, 256 blocks (1/CU).
// Redundancy 1.67x, 4 steps/launch, 32 launches — same as R14 structure.
#define NSITES (2 * 128 * 128 * 8)      // 262144
#define NBLK   256                      // 16 bx * 8 by * 2 pp
#define NSUP   32                       // 32 launches x 4 fused steps = 128
#define TLX    16                       // staged cols x: 8 own + 4+4 halo
#define TLY    24                       // staged cols y: 16 own + 4+4 halo
#define NCOL   (TLX * TLY)              // 384 columns, 1 per thread

union F4 { float4 v; float f[4]; };
union U2 { ulonglong2 v; unsigned long long u[2]; unsigned w[4]; };

// bf16 helpers (RNE). Every block rounds identical register values
// identically, so cross-block redundant-compute consistency is bitwise-exact.
__device__ __forceinline__ unsigned bf_rnd(float v) {
    const unsigned u = __float_as_uint(v);
    return (u + 0x7FFFu + ((u >> 16) & 1u)) >> 16;
}
__device__ __forceinline__ float bf_lo(unsigned p) { return __uint_as_float(p << 16); }
__device__ __forceinline__ float bf_hi(unsigned p) { return __uint_as_float(p & 0xFFFF0000u); }
__device__ __forceinline__ unsigned pk_bf2(float lo, float hi) {
    return bf_rnd(lo) | (bf_rnd(hi) << 16);
}

template <bool FIRST, bool LAST>
__global__ __launch_bounds__(384, 2) void pdhg_col(
    const float* __restrict__ x,
    const float* __restrict__ lam,
    const float* __restrict__ tau_p,
    const float* __restrict__ sigma_p,
    const float* __restrict__ theta_p,
    const unsigned long long* __restrict__ inD1,   // bf16x4 {xb,q0,q1,q2}
    const unsigned long long* __restrict__ inD2,   // fp32x2 {p,x0}
    unsigned long long* __restrict__ outD1,
    unsigned long long* __restrict__ outD2,
    float* __restrict__ out_final)
{
    // [buf][Tplane (4 T each)][col]: 24 KB + 24 KB
    __shared__ float4     Lxb[2][2][NCOL];
    __shared__ ulonglong2 Lqq[2][2][NCOL];

    // XCD-arc swizzle (L2-locality heuristic only)
    const int b  = 32 * (blockIdx.x & 7) + (blockIdx.x >> 3);
    const int pp = b >> 7;
    const int rr = b & 127;
    const int bx = rr >> 3;        // [0,16)
    const int by = rr & 7;         // [0,8)

    const int t  = threadIdx.x;    // [0,384)
    const int lx = t / TLY;        // [0,16)
    const int ly = t - lx * TLY;   // [0,24)

    const int X  = ((bx << 3) + lx - 4) & 127;
    const int Y  = ((by << 4) + ly - 4) & 127;
    const int Xm = (X + 127) & 127;
    const int Ym = (Y + 127) & 127;

    const int gcol = (pp << 17) | (X << 10) | (Y << 3);   // site idx of T=0
    const int gxm  = (pp << 17) | (Xm << 10) | (Y << 3);
    const int gym  = (pp << 17) | (X << 10) | (Ym << 3);

    // widest computed region (h=3): lx in [1,15), ly in [1,23)
    const bool comp = (lx >= 1) && (lx < 15) && (ly >= 1) && (ly < 23);

    const float L = 3.605551275463989f;  // sqrt(13)
    const float s_sig = (1.f / (1.f + __expf(-sigma_p[0]))) / L;
    const float s_tau = (1.f / (1.f + __expf(-tau_p[0]))) / L;
    const float s_th  =  1.f / (1.f + __expf(-theta_p[0]));
    const float inv1s = 1.f / (1.f + s_sig);

    float xn[8], lamc[8], lamx[8], lamy[8];
    {
        const float4* x4 = (const float4*)x;
        const float4* l4 = (const float4*)lam;
        if (FIRST || comp) {
            F4 a, c; a.v = x4[gcol >> 2]; c.v = x4[(gcol >> 2) + 1];
            #pragma unroll
            for (int j = 0; j < 4; ++j) { xn[j] = a.f[j]; xn[j + 4] = c.f[j]; }
        } else {
            #pragma unroll
            for (int j = 0; j < 8; ++j) xn[j] = 0.f;
        }
        if (comp) {
            F4 a, c;
            a.v = l4[gcol >> 2]; c.v = l4[(gcol >> 2) + 1];
            #pragma unroll
            for (int j = 0; j < 4; ++j) { lamc[j] = a.f[j]; lamc[j + 4] = c.f[j]; }
            a.v = l4[gxm >> 2]; c.v = l4[(gxm >> 2) + 1];
            #pragma unroll
            for (int j = 0; j < 4; ++j) { lamx[j] = a.f[j]; lamx[j + 4] = c.f[j]; }
            a.v = l4[gym >> 2]; c.v = l4[(gym >> 2) + 1];
            #pragma unroll
            for (int j = 0; j < 4; ++j) { lamy[j] = a.f[j]; lamy[j + 4] = c.f[j]; }
        } else {
            #pragma unroll
            for (int j = 0; j < 8; ++j) { lamc[j] = 0.f; lamx[j] = 0.f; lamy[j] = 0.f; }
        }
    }

    float x0[8], p[8], q0[8], q1[8], q2[8], xb[8];
    if (FIRST) {
        #pragma unroll
        for (int j = 0; j < 8; ++j) {
            const float v = xn[j];
            x0[j] = v; p[j] = v; xb[j] = v;
            q0[j] = 0.f; q1[j] = 0.f; q2[j] = 0.f;
        }
    } else {
        const ulonglong2* d1 = (const ulonglong2*)inD1;
        #pragma unroll
        for (int k = 0; k < 4; ++k) {
            U2 a; a.v = d1[(gcol >> 1) + k];
            #pragma unroll
            for (int m = 0; m < 2; ++m) {
                const int j = 2 * k + m;
                const unsigned lo = a.w[2 * m], hi = a.w[2 * m + 1];
                xb[j] = bf_lo(lo); q0[j] = bf_hi(lo);
                q1[j] = bf_lo(hi); q2[j] = bf_hi(hi);
            }
        }
        if (comp) {
            const float4* d2 = (const float4*)inD2;
            #pragma unroll
            for (int k = 0; k < 4; ++k) {
                F4 a; a.v = d2[(gcol >> 1) + k];
                p[2 * k]      = a.f[0]; x0[2 * k]     = a.f[1];
                p[2 * k + 1]  = a.f[2]; x0[2 * k + 1] = a.f[3];
            }
        } else {
            #pragma unroll
            for (int j = 0; j < 8; ++j) { p[j] = 0.f; x0[j] = 0.f; }
        }
    }

    auto clip = [](float v, float l) { return fmaxf(-l, fminf(l, v)); };

    // one fused sub-step: compute lx in [4-h,12+h), ly in [4-h,20+h)
    // store-mask = compute-region(h+1): [3-h,13+h) x [3-h,21+h)
    // Double-buffered LDS (pb = h&1): one barrier per sub-step; two barriers
    // separate reuse of the same buffer.
    auto substep = [&](const int h) {
        const int pb = h & 1;
        if (lx >= 3 - h && lx < 13 + h && ly >= 3 - h && ly < 21 + h) {
            Lxb[pb][0][t] = make_float4(xb[0], xb[1], xb[2], xb[3]);
            Lxb[pb][1][t] = make_float4(xb[4], xb[5], xb[6], xb[7]);
            U2 w0, w1;
            w0.w[0] = pk_bf2(q0[0], q1[0]); w0.w[1] = pk_bf2(q0[1], q1[1]);
            w0.w[2] = pk_bf2(q0[2], q1[2]); w0.w[3] = pk_bf2(q0[3], q1[3]);
            w1.w[0] = pk_bf2(q0[4], q1[4]); w1.w[1] = pk_bf2(q0[5], q1[5]);
            w1.w[2] = pk_bf2(q0[6], q1[6]); w1.w[3] = pk_bf2(q0[7], q1[7]);
            Lqq[pb][0][t] = w0.v;
            Lqq[pb][1][t] = w1.v;
        }
        __syncthreads();
        if (lx >= 4 - h && lx < 12 + h && ly >= 4 - h && ly < 20 + h) {
            float oxb[8], oq2[8];
            #pragma unroll
            for (int j = 0; j < 8; ++j) { oxb[j] = xb[j]; oq2[j] = q2[j]; }
            #pragma unroll
            for (int k = 0; k < 2; ++k) {
                F4 xp, xm, yp, ym; U2 qx, qy;
                xp.v = Lxb[pb][k][t + TLY];
                xm.v = Lxb[pb][k][t - TLY];
                yp.v = Lxb[pb][k][t + 1];
                ym.v = Lxb[pb][k][t - 1];
                qx.v = Lqq[pb][k][t - TLY];
                qy.v = Lqq[pb][k][t - 1];
                #pragma unroll
                for (int j2 = 0; j2 < 4; ++j2) {
                    const int j  = 4 * k + j2;
                    const int jm = (j + 7) & 7;
                    const float ob  = oxb[j];
                    const float pn  = (p[j] + s_sig * (ob - xn[j])) * inv1s;
                    const float q0n = clip(q0[j]  + s_sig * (xp.f[j2] - ob), lamc[j]);
                    const float q1n = clip(q1[j]  + s_sig * (yp.f[j2] - ob), lamc[j]);
                    const float q2n = clip(oq2[j] + s_sig * (oxb[(j + 1) & 7] - ob), lamc[j]);
                    const float q0m = clip(bf_lo(qx.w[j2]) + s_sig * (ob - xm.f[j2]), lamx[j]);
                    const float q1m = clip(bf_hi(qy.w[j2]) + s_sig * (ob - ym.f[j2]), lamy[j]);
                    const float q2m = clip(oq2[jm] + s_sig * (ob - oxb[jm]), lamc[jm]);
                    const float dv  = (q0m - q0n) + (q1m - q1n) + (q2m - q2n);
                    const float x1  = x0[j] - s_tau * (pn + dv);
                    xb[j] = x1 + s_th * (x1 - x0[j]);
                    x0[j] = x1; p[j] = pn;
                    q0[j] = q0n; q1[j] = q1n; q2[j] = q2n;
                }
            }
        }
    };

    substep(3);   // step 4g+1 on 14x22
    substep(2);   // step 4g+2 on 12x20
    substep(1);   // step 4g+3 on 10x18
    substep(0);   // step 4g+4 on  8x16 (own)

    // write authoritative own sites only
    if (lx >= 4 && lx < 12 && ly >= 4 && ly < 20) {
        if (LAST) {
            float4* o4 = (float4*)out_final;
            F4 a, c;
            a.f[0] = x0[0]; a.f[1] = x0[1]; a.f[2] = x0[2]; a.f[3] = x0[3];
            c.f[0] = x0[4]; c.f[1] = x0[5]; c.f[2] = x0[6]; c.f[3] = x0[7];
            o4[gcol >> 2] = a.v;
            o4[(gcol >> 2) + 1] = c.v;
        } else {
            ulonglong2* o1 = (ulonglong2*)outD1;
            float4*     o2 = (float4*)outD2;
            #pragma unroll
            for (int k = 0; k < 4; ++k) {
                U2 w;
                #pragma unroll
                for (int m = 0; m < 2; ++m) {
                    const int j = 2 * k + m;
                    w.w[2 * m]     = pk_bf2(xb[j], q0[j]);
                    w.w[2 * m + 1] = pk_bf2(q1[j], q2[j]);
                }
                o1[(gcol >> 1) + k] = w.v;
                F4 d;
                d.f[0] = p[2 * k];     d.f[1] = x0[2 * k];
                d.f[2] = p[2 * k + 1]; d.f[3] = x0[2 * k + 1];
                o2[(gcol >> 1) + k] = d.v;
            }
        }
    }
}

extern "C" void kernel_launch(void* const* d_in, const int* in_sizes, int n_in,
                              void* d_out, int out_size, void* d_ws, size_t ws_size,
                              hipStream_t stream) {
    const float* x   = (const float*)d_in[0];
    const float* lam = (const float*)d_in[1];
    const float* tau = (const float*)d_in[2];
    const float* sig = (const float*)d_in[3];
    const float* th  = (const float*)d_in[4];
    float* out = (float*)d_out;

    // ws layout: D1 (2 slots u64, 4 MB), D2 (2 slots u64, 4 MB)
    unsigned long long* D1 = (unsigned long long*)d_ws;
    unsigned long long* D2 = D1 + 2 * (size_t)NSITES;

    dim3 grid(NBLK), block(TLX * TLY);

    for (int g = 0; g < NSUP; ++g) {
        const size_t si = (size_t)((g + 1) & 1) * NSITES;  // read slot (prev write)
        const size_t so = (size_t)(g & 1) * NSITES;        // write slot
        const unsigned long long *i1 = D1 + si, *i2 = D2 + si;
        unsigned long long *o1 = D1 + so, *o2 = D2 + so;
        if (g == 0) {
            pdhg_col<true, false><<<grid, block, 0, stream>>>(
                x, lam, tau, sig, th, i1, i2, o1, o2, out);
        } else if (g == NSUP - 1) {
            pdhg_col<false, true><<<grid, block, 0, stream>>>(
                x, lam, tau, sig, th, i1, i2, o1, o2, out);
        } else {
            pdhg_col<false, false><<<grid, block, 0, stream>>>(
                x, lam, tau, sig, th, i1, i2, o1, o2, out);
        }
    }
}

// Round 3
// 285.201 us; speedup vs baseline: 1.2325x; 1.2325x over previous
//
#include <hip/hip_runtime.h>
#include <math.h>

// (P, C, NX, NY, NT) = (2, 1, 128, 128, 8), T = 128
// Layout: idx = pp<<17 | X<<10 | Y<<3 | T
// R2: split-T columns. Each thread owns 4 consecutive T of one (x,y) column
// (partner thread in adjacent lane owns the other 4; T-boundary via
// shfl_xor(1)). 768 threads/block = 12 waves/CU (vs R1's 6) at the same
// 1.67x redundancy; LDS staging stays b128-vectorized and contiguous
// (address = t*16B +/- const). VGPR ~halved vs R1.
#define NSITES (2 * 128 * 128 * 8)      // 262144
#define NBLK   256                      // 16 bx * 8 by * 2 pp
#define NSUP   32                       // 32 launches x 4 fused steps = 128
#define TLX    16                       // staged cols x: 8 own + 4+4 halo
#define TLY    24                       // staged cols y: 16 own + 4+4 halo
#define NCOL   (TLX * TLY)              // 384 columns
#define NTHR   (NCOL * 2)               // 768 threads, 2 per column

union F4 { float4 v; float f[4]; };
union U4 { uint4 v; unsigned w[4]; };

// bf16 helpers (RNE). Every block rounds identical register values
// identically, so cross-block redundant-compute consistency is bitwise-exact.
__device__ __forceinline__ unsigned bf_rnd(float v) {
    const unsigned u = __float_as_uint(v);
    return (u + 0x7FFFu + ((u >> 16) & 1u)) >> 16;
}
__device__ __forceinline__ float bf_lo(unsigned p) { return __uint_as_float(p << 16); }
__device__ __forceinline__ float bf_hi(unsigned p) { return __uint_as_float(p & 0xFFFF0000u); }
__device__ __forceinline__ unsigned pk_bf2(float lo, float hi) {
    return bf_rnd(lo) | (bf_rnd(hi) << 16);
}

template <bool FIRST, bool LAST>
__global__ __launch_bounds__(NTHR, 3) void pdhg_col(
    const float* __restrict__ x,
    const float* __restrict__ lam,
    const float* __restrict__ tau_p,
    const float* __restrict__ sigma_p,
    const float* __restrict__ theta_p,
    const unsigned long long* __restrict__ inD1,   // bf16x4 {xb,q0,q1,q2}
    const unsigned long long* __restrict__ inD2,   // fp32x2 {p,x0}
    unsigned long long* __restrict__ outD1,
    unsigned long long* __restrict__ outD2,
    float* __restrict__ out_final)
{
    // [buf][t]: t = col*2 + tm, so writes/reads are t*16B +/- const (no conflicts)
    __shared__ float4 Lxb[2][NTHR];   // 24 KB  xb fp32x4 (4 T of one chunk)
    __shared__ uint4  Lqq[2][NTHR];   // 24 KB  bf16x2 {q0,q1} x4 T

    // XCD-arc swizzle (L2-locality heuristic only)
    const int b  = 32 * (blockIdx.x & 7) + (blockIdx.x >> 3);
    const int pp = b >> 7;
    const int rr = b & 127;
    const int bx = rr >> 3;        // [0,16)
    const int by = rr & 7;         // [0,8)

    const int t   = threadIdx.x;   // [0,768)
    const int tm  = t & 1;         // T-chunk: sites tm*4 .. tm*4+3
    const int col = t >> 1;        // [0,384)
    const int lx  = col / TLY;     // [0,16)
    const int ly  = col - lx * TLY;// [0,24)

    const int X  = ((bx << 3) + lx - 4) & 127;
    const int Y  = ((by << 4) + ly - 4) & 127;
    const int Xm = (X + 127) & 127;
    const int Ym = (Y + 127) & 127;

    const int gcol = (pp << 17) | (X << 10) | (Y << 3);   // site idx of T=0
    const int gxm  = (pp << 17) | (Xm << 10) | (Y << 3);
    const int gym  = (pp << 17) | (X << 10) | (Ym << 3);

    // widest computed region (h=3): lx in [1,15), ly in [1,23)
    const bool comp = (lx >= 1) && (lx < 15) && (ly >= 1) && (ly < 23);

    const float L = 3.605551275463989f;  // sqrt(13)
    const float s_sig = (1.f / (1.f + __expf(-sigma_p[0]))) / L;
    const float s_tau = (1.f / (1.f + __expf(-tau_p[0]))) / L;
    const float s_th  =  1.f / (1.f + __expf(-theta_p[0]));
    const float inv1s = 1.f / (1.f + s_sig);

    const int c4 = (gcol >> 2) + tm;   // float4 index of this chunk

    float xn[4], lamc[4], lamx[4], lamy[4];
    {
        const float4* x4 = (const float4*)x;
        const float4* l4 = (const float4*)lam;
        if (FIRST || comp) {
            F4 a; a.v = x4[c4];
            #pragma unroll
            for (int j = 0; j < 4; ++j) xn[j] = a.f[j];
        } else {
            #pragma unroll
            for (int j = 0; j < 4; ++j) xn[j] = 0.f;
        }
        if (comp) {
            F4 a;
            a.v = l4[c4];
            #pragma unroll
            for (int j = 0; j < 4; ++j) lamc[j] = a.f[j];
            a.v = l4[(gxm >> 2) + tm];
            #pragma unroll
            for (int j = 0; j < 4; ++j) lamx[j] = a.f[j];
            a.v = l4[(gym >> 2) + tm];
            #pragma unroll
            for (int j = 0; j < 4; ++j) lamy[j] = a.f[j];
        } else {
            #pragma unroll
            for (int j = 0; j < 4; ++j) { lamc[j] = 0.f; lamx[j] = 0.f; lamy[j] = 0.f; }
        }
    }
    // lam at the T-1 site of this chunk's first element = partner's lamc[3]
    const float lamtm = __shfl_xor(lamc[3], 1, 64);

    float x0[4], p[4], q0[4], q1[4], q2[4], xb[4];
    if (FIRST) {
        #pragma unroll
        for (int j = 0; j < 4; ++j) {
            const float v = xn[j];
            x0[j] = v; p[j] = v; xb[j] = v;
            q0[j] = 0.f; q1[j] = 0.f; q2[j] = 0.f;
        }
    } else {
        const uint4* d1 = (const uint4*)inD1;       // 2 sites per uint4
        const int base = (gcol >> 1) + 2 * tm;      // 16B-granule index
        #pragma unroll
        for (int k = 0; k < 2; ++k) {
            U4 a; a.v = d1[base + k];
            #pragma unroll
            for (int m = 0; m < 2; ++m) {
                const int j = 2 * k + m;
                const unsigned lo = a.w[2 * m], hi = a.w[2 * m + 1];
                xb[j] = bf_lo(lo); q0[j] = bf_hi(lo);
                q1[j] = bf_lo(hi); q2[j] = bf_hi(hi);
            }
        }
        if (comp) {
            const float4* d2 = (const float4*)inD2;  // 2 sites per float4
            #pragma unroll
            for (int k = 0; k < 2; ++k) {
                F4 a; a.v = d2[base + k];
                p[2 * k]     = a.f[0]; x0[2 * k]     = a.f[1];
                p[2 * k + 1] = a.f[2]; x0[2 * k + 1] = a.f[3];
            }
        } else {
            #pragma unroll
            for (int j = 0; j < 4; ++j) { p[j] = 0.f; x0[j] = 0.f; }
        }
    }

    auto clip = [](float v, float l) { return fmaxf(-l, fminf(l, v)); };

    // one fused sub-step: compute lx in [4-h,12+h), ly in [4-h,20+h)
    // store-mask = compute-region(h+1): [3-h,13+h) x [3-h,21+h)
    // Double-buffered LDS (pb = h&1): one barrier per sub-step; two barriers
    // separate reuse of the same buffer. Partner lanes share (lx,ly) so all
    // masks are pairwise-uniform and shfl_xor(1) partners are co-active.
    auto substep = [&](const int h) {
        const int pb = h & 1;
        if (lx >= 3 - h && lx < 13 + h && ly >= 3 - h && ly < 21 + h) {
            Lxb[pb][t] = make_float4(xb[0], xb[1], xb[2], xb[3]);
            U4 w;
            w.w[0] = pk_bf2(q0[0], q1[0]); w.w[1] = pk_bf2(q0[1], q1[1]);
            w.w[2] = pk_bf2(q0[2], q1[2]); w.w[3] = pk_bf2(q0[3], q1[3]);
            Lqq[pb][t] = w.v;
        }
        __syncthreads();
        if (lx >= 4 - h && lx < 12 + h && ly >= 4 - h && ly < 20 + h) {
            // T-boundary values from partner chunk (pre-update snapshots)
            const float xb_tp = __shfl_xor(xb[0], 1, 64);  // T+1 past chunk end
            const float xb_tm = __shfl_xor(xb[3], 1, 64);  // T-1 before chunk start
            const float q2_tm = __shfl_xor(q2[3], 1, 64);
            F4 xp, xm, yp, ym; U4 qx, qy;
            xp.v = Lxb[pb][t + 2 * TLY];
            xm.v = Lxb[pb][t - 2 * TLY];
            yp.v = Lxb[pb][t + 2];
            ym.v = Lxb[pb][t - 2];
            qx.v = Lqq[pb][t - 2 * TLY];
            qy.v = Lqq[pb][t - 2];
            float oxb[4], oq2[4];
            #pragma unroll
            for (int j = 0; j < 4; ++j) { oxb[j] = xb[j]; oq2[j] = q2[j]; }
            #pragma unroll
            for (int j = 0; j < 4; ++j) {
                const float ob   = oxb[j];
                const float xbtp = (j < 3) ? oxb[j + 1] : xb_tp;
                const float xbtm = (j > 0) ? oxb[j - 1] : xb_tm;
                const float q2tm = (j > 0) ? oq2[j - 1] : q2_tm;
                const float lT   = (j > 0) ? lamc[j - 1] : lamtm;
                const float pn  = (p[j] + s_sig * (ob - xn[j])) * inv1s;
                const float q0n = clip(q0[j] + s_sig * (xp.f[j] - ob), lamc[j]);
                const float q1n = clip(q1[j] + s_sig * (yp.f[j] - ob), lamc[j]);
                const float q2n = clip(oq2[j] + s_sig * (xbtp - ob), lamc[j]);
                const float q0m = clip(bf_lo(qx.w[j]) + s_sig * (ob - xm.f[j]), lamx[j]);
                const float q1m = clip(bf_hi(qy.w[j]) + s_sig * (ob - ym.f[j]), lamy[j]);
                const float q2m = clip(q2tm + s_sig * (ob - xbtm), lT);
                const float dv  = (q0m - q0n) + (q1m - q1n) + (q2m - q2n);
                const float x1  = x0[j] - s_tau * (pn + dv);
                xb[j] = x1 + s_th * (x1 - x0[j]);
                x0[j] = x1; p[j] = pn;
                q0[j] = q0n; q1[j] = q1n; q2[j] = q2n;
            }
        }
    };

    substep(3);   // step 4g+1 on 14x22
    substep(2);   // step 4g+2 on 12x20
    substep(1);   // step 4g+3 on 10x18
    substep(0);   // step 4g+4 on  8x16 (own)

    // write authoritative own sites only
    if (lx >= 4 && lx < 12 && ly >= 4 && ly < 20) {
        if (LAST) {
            float4* o4 = (float4*)out_final;
            F4 a;
            a.f[0] = x0[0]; a.f[1] = x0[1]; a.f[2] = x0[2]; a.f[3] = x0[3];
            o4[c4] = a.v;
        } else {
            uint4*  o1 = (uint4*)outD1;
            float4* o2 = (float4*)outD2;
            const int base = (gcol >> 1) + 2 * tm;
            #pragma unroll
            for (int k = 0; k < 2; ++k) {
                U4 w;
                #pragma unroll
                for (int m = 0; m < 2; ++m) {
                    const int j = 2 * k + m;
                    w.w[2 * m]     = pk_bf2(xb[j], q0[j]);
                    w.w[2 * m + 1] = pk_bf2(q1[j], q2[j]);
                }
                o1[base + k] = w.v;
                F4 d;
                d.f[0] = p[2 * k];     d.f[1] = x0[2 * k];
                d.f[2] = p[2 * k + 1]; d.f[3] = x0[2 * k + 1];
                o2[base + k] = d.v;
            }
        }
    }
}

extern "C" void kernel_launch(void* const* d_in, const int* in_sizes, int n_in,
                              void* d_out, int out_size, void* d_ws, size_t ws_size,
                              hipStream_t stream) {
    const float* x   = (const float*)d_in[0];
    const float* lam = (const float*)d_in[1];
    const float* tau = (const float*)d_in[2];
    const float* sig = (const float*)d_in[3];
    const float* th  = (const float*)d_in[4];
    float* out = (float*)d_out;

    // ws layout: D1 (2 slots u64, 4 MB), D2 (2 slots u64, 4 MB)
    unsigned long long* D1 = (unsigned long long*)d_ws;
    unsigned long long* D2 = D1 + 2 * (size_t)NSITES;

    dim3 grid(NBLK), block(NTHR);

    for (int g = 0; g < NSUP; ++g) {
        const size_t si = (size_t)((g + 1) & 1) * NSITES;  // read slot (prev write)
        const size_t so = (size_t)(g & 1) * NSITES;        // write slot
        const unsigned long long *i1 = D1 + si, *i2 = D2 + si;
        unsigned long long *o1 = D1 + so, *o2 = D2 + so;
        if (g == 0) {
            pdhg_col<true, false><<<grid, block, 0, stream>>>(
                x, lam, tau, sig, th, i1, i2, o1, o2, out);
        } else if (g == NSUP - 1) {
            pdhg_col<false, true><<<grid, block, 0, stream>>>(
                x, lam, tau, sig, th, i1, i2, o1, o2, out);
        } else {
            pdhg_col<false, false><<<grid, block, 0, stream>>>(
                x, lam, tau, sig, th, i1, i2, o1, o2, out);
        }
    }
}